// Round 3
// baseline (934.840 us; speedup 1.0000x reference)
//
#include <hip/hip_runtime.h>
#include <math.h>

#define VOCAB 8000
#define BATCH 128
#define TMAX  512
#define DIM   256
#define HID   128
#define G4    512     // 4*HID
#define NCOL  1024    // 2*G4 (both directions)

// ---------------------------------------------------------------------------
// Kernel 1: embW[v][n] = emb[v,:] . W_ih_dir[n,:] + b_ih_dir[n] + b_hh_dir[n]
// ---------------------------------------------------------------------------
__global__ __launch_bounds__(256) void embw_gemm(
    const float* __restrict__ emb,
    const float* __restrict__ Wf, const float* __restrict__ Wb,
    const float* __restrict__ bihf, const float* __restrict__ bhhf,
    const float* __restrict__ bihb, const float* __restrict__ bhhb,
    float* __restrict__ embW) {
  __shared__ float As[32][132];   // k-major, padded stride
  __shared__ float Bs[32][132];
  const int tid = threadIdx.x;
  const int m0 = blockIdx.x * 128;
  const int n0 = blockIdx.y * 128;
  const int tx = tid & 15, ty = tid >> 4;
  const int lrow = tid >> 1;            // 0..127
  const int lseg = (tid & 1) * 16;      // 0 or 16 (k offset)
  const float* Wsrc = (n0 < 512) ? Wf : Wb;
  const int nbase = (n0 < 512) ? n0 : (n0 - 512);

  float acc[8][8];
  #pragma unroll
  for (int i = 0; i < 8; ++i)
    #pragma unroll
    for (int jj = 0; jj < 8; ++jj) acc[i][jj] = 0.f;

  for (int k0 = 0; k0 < 256; k0 += 32) {
    const int gm = m0 + lrow;
    #pragma unroll
    for (int q = 0; q < 4; ++q) {
      float4 v = make_float4(0.f, 0.f, 0.f, 0.f);
      if (gm < VOCAB) v = *(const float4*)(emb + (size_t)gm * 256 + k0 + lseg + 4 * q);
      As[lseg + 4*q + 0][lrow] = v.x;
      As[lseg + 4*q + 1][lrow] = v.y;
      As[lseg + 4*q + 2][lrow] = v.z;
      As[lseg + 4*q + 3][lrow] = v.w;
    }
    #pragma unroll
    for (int q = 0; q < 4; ++q) {
      float4 v = *(const float4*)(Wsrc + (size_t)(nbase + lrow) * 256 + k0 + lseg + 4 * q);
      Bs[lseg + 4*q + 0][lrow] = v.x;
      Bs[lseg + 4*q + 1][lrow] = v.y;
      Bs[lseg + 4*q + 2][lrow] = v.z;
      Bs[lseg + 4*q + 3][lrow] = v.w;
    }
    __syncthreads();
    #pragma unroll
    for (int k = 0; k < 32; ++k) {
      float4 av0 = *(const float4*)&As[k][ty * 8];
      float4 av1 = *(const float4*)&As[k][ty * 8 + 4];
      float4 bv0 = *(const float4*)&Bs[k][tx * 4];
      float4 bv1 = *(const float4*)&Bs[k][64 + tx * 4];
      float a[8]  = {av0.x, av0.y, av0.z, av0.w, av1.x, av1.y, av1.z, av1.w};
      float bb[8] = {bv0.x, bv0.y, bv0.z, bv0.w, bv1.x, bv1.y, bv1.z, bv1.w};
      #pragma unroll
      for (int i = 0; i < 8; ++i)
        #pragma unroll
        for (int jj = 0; jj < 8; ++jj)
          acc[i][jj] += a[i] * bb[jj];
    }
    __syncthreads();
  }

  float bias[8];
  #pragma unroll
  for (int jj = 0; jj < 8; ++jj) {
    int n = n0 + ((jj < 4) ? (tx * 4 + jj) : (64 + tx * 4 + (jj - 4)));
    bias[jj] = (n < 512) ? (bihf[n] + bhhf[n]) : (bihb[n - 512] + bhhb[n - 512]);
  }
  #pragma unroll
  for (int i = 0; i < 8; ++i) {
    int gm = m0 + ty * 8 + i;
    if (gm >= VOCAB) continue;
    float4 v0 = make_float4(acc[i][0] + bias[0], acc[i][1] + bias[1],
                            acc[i][2] + bias[2], acc[i][3] + bias[3]);
    float4 v1 = make_float4(acc[i][4] + bias[4], acc[i][5] + bias[5],
                            acc[i][6] + bias[6], acc[i][7] + bias[7]);
    *(float4*)(embW + (size_t)gm * NCOL + n0 + tx * 4) = v0;
    *(float4*)(embW + (size_t)gm * NCOL + n0 + 64 + tx * 4) = v1;
  }
}

// ---------------------------------------------------------------------------
// Kernel 2: masked LSTM recurrence. One block per (seq, dir); 256 blocks =
// 1 per CU. tid = 4*j + g. W_hh row in 32 named float4 SSA values.
// amdgpu_waves_per_eu(2,2): min=max=2 waves/EU -> 256-VGPR budget, removes
// the occupancy incentive that made the compiler sink weight loads into the
// loop (R1: alloca->scratch @104 VGPR; R2: load-sink @88 VGPR, VALUBusy 35%).
// ---------------------------------------------------------------------------
#define REP32(M) M(0) M(1) M(2) M(3) M(4) M(5) M(6) M(7) M(8) M(9) M(10) \
  M(11) M(12) M(13) M(14) M(15) M(16) M(17) M(18) M(19) M(20) M(21) M(22) \
  M(23) M(24) M(25) M(26) M(27) M(28) M(29) M(30) M(31)

__global__ __launch_bounds__(512)
__attribute__((amdgpu_waves_per_eu(2, 2)))
void lstm_rec(
    const int* __restrict__ pad_seq, const int* __restrict__ lens,
    const float* __restrict__ Whh_f, const float* __restrict__ Whh_b,
    const float* __restrict__ embW, float* __restrict__ h_out) {
  const int dir = blockIdx.x & 1;
  const int b = blockIdx.x >> 1;
  const int tid = threadIdx.x;
  const int j = tid >> 2;       // hidden unit 0..127
  const int g = tid & 3;        // gate 0..3 (i,f,g,o)
  __shared__ float h_buf[2][HID];
  __shared__ int tok[TMAX];

  tok[tid] = pad_seq[b * TMAX + tid];
  if (tid < HID) h_buf[0][tid] = 0.f;
  const int len = lens[b];
  const float* __restrict__ Whh = dir ? Whh_b : Whh_f;

  // W_hh row (g*HID + j), 128 floats, in 32 named float4 SSA values
  const float4* wr = (const float4*)(Whh + (size_t)(g * HID + j) * HID);
#define DECLW(i) float4 w##i = wr[i];
  REP32(DECLW)
#undef DECLW

  float c = 0.f;
  __syncthreads();

  const float* __restrict__ ecol = embW + dir * G4 + (g * HID + j);
  const int tstep = dir ? -1 : 1;
  int t = dir ? (len - 1) : 0;
  float xw0 = ecol[(size_t)tok[t] * NCOL];                     // step s
  float xw1 = (len > 1) ? ecol[(size_t)tok[t + tstep] * NCOL] : 0.f;  // s+1

  for (int s = 0; s < len; ++s) {
    // depth-2 prefetch: step s+2 (covers ~900cyc HBM-miss latency)
    float xw2 = 0.f;
    if (s + 2 < len) xw2 = ecol[(size_t)tok[t + 2 * tstep] * NCOL];

    const float4* h4 = (const float4*)h_buf[s & 1];
    float a0 = 0.f, a1 = 0.f, a2 = 0.f, a3 = 0.f;
#define MAC(i) { float4 hv = h4[i];                 \
    a0 = fmaf(hv.x, w##i.x, a0);                    \
    a1 = fmaf(hv.y, w##i.y, a1);                    \
    a2 = fmaf(hv.z, w##i.z, a2);                    \
    a3 = fmaf(hv.w, w##i.w, a3); }
    REP32(MAC)
#undef MAC
    // fold gather in last so the vmcnt wait lands after the FMA stream
    const float a = ((a0 + a1) + (a2 + a3)) + xw0;

    // quad exchange: lane (4j+g) -> all four gate values of unit j
    const float p1 = __shfl_xor(a, 1);    // gate g^1
    const float p2 = __shfl_xor(a, 2);    // gate g^2
    const float p3 = __shfl_xor(p1, 2);   // gate g^3
    const float ev  = (g & 1) ? p1 : a;
    const float od  = (g & 1) ? a  : p1;
    const float ev2 = (g & 1) ? p3 : p2;
    const float od2 = (g & 1) ? p2 : p3;
    const float gi = (g & 2) ? ev2 : ev;
    const float gf = (g & 2) ? od2 : od;
    const float gg = (g & 2) ? ev  : ev2;
    const float go = (g & 2) ? od  : od2;

    const float ig = 1.f / (1.f + expf(-gi));
    const float fg = 1.f / (1.f + expf(-gf));
    const float og = 1.f / (1.f + expf(-go));
    c = fg * c + ig * tanhf(gg);          // redundant x4 per quad, identical
    const float h = og * tanhf(c);

    if (g == 0) {
      h_buf[(s + 1) & 1][j] = h;
      h_out[((size_t)(b * TMAX + t)) * DIM + dir * HID + j] = h;
    }
    __syncthreads();                      // single barrier per step
    xw0 = xw1; xw1 = xw2;
    t += tstep;
  }
}

// ---------------------------------------------------------------------------
// Kernel 3: emissions + Viterbi. DP quad-parallel (lane l = cur label) with
// sc prefetch -> per-step chain ~35 cyc instead of LDS-latency-bound serial.
// ---------------------------------------------------------------------------
__global__ __launch_bounds__(512) void viterbi_k(
    const int* __restrict__ lens, const float* __restrict__ h_out,
    const float* __restrict__ W_lab, const float* __restrict__ b_lab,
    const float* __restrict__ trans, const float* __restrict__ from_BOS,
    const float* __restrict__ to_EOS, int* __restrict__ out) {
  const int b = blockIdx.x;
  const int tid = threadIdx.x;
  __shared__ float sc[TMAX][4];
  __shared__ unsigned btm[TMAX];
  __shared__ float wl[4][256];
  __shared__ int labs[TMAX];
  const int len = lens[b];

  for (int i = tid; i < 1024; i += 512) wl[i >> 8][i & 255] = W_lab[i];
  __syncthreads();

  if (tid < len) {
    const float4* h4 = (const float4*)(h_out + ((size_t)(b * TMAX + tid)) * DIM);
    float s0 = b_lab[0], s1 = b_lab[1], s2 = b_lab[2], s3 = b_lab[3];
    #pragma unroll 8
    for (int k4 = 0; k4 < 64; ++k4) {
      float4 hv = h4[k4];
      float4 w0 = *(const float4*)&wl[0][4 * k4];
      float4 w1 = *(const float4*)&wl[1][4 * k4];
      float4 w2 = *(const float4*)&wl[2][4 * k4];
      float4 w3 = *(const float4*)&wl[3][4 * k4];
      s0 += hv.x * w0.x + hv.y * w0.y + hv.z * w0.z + hv.w * w0.w;
      s1 += hv.x * w1.x + hv.y * w1.y + hv.z * w1.z + hv.w * w1.w;
      s2 += hv.x * w2.x + hv.y * w2.y + hv.z * w2.z + hv.w * w2.w;
      s3 += hv.x * w3.x + hv.y * w3.y + hv.z * w3.z + hv.w * w3.w;
    }
    *(float4*)&sc[tid][0] = make_float4(s0, s1, s2, s3);
  }
  __syncthreads();

  // --- DP: lanes 0..3 of wave 0, lane l owns cur-label l ---
  if (tid < 4) {
    const int l = tid;
    float trc0 = trans[0 * 4 + l], trc1 = trans[1 * 4 + l];
    float trc2 = trans[2 * 4 + l], trc3 = trans[3 * 4 + l];
    float best = from_BOS[l] + sc[0][l];
    float e_next = sc[1][l];                 // prefetch (unused if len==1)
    for (int ti = 1; ti < len; ++ti) {
      const float e = e_next;
      e_next = sc[(ti + 1 < TMAX) ? ti + 1 : ti][l];   // prefetch next
      const float b0 = __shfl(best, 0);
      const float b1 = __shfl(best, 1);
      const float b2 = __shfl(best, 2);
      const float b3 = __shfl(best, 3);
      // reference add order: (best[p] + e[cur]) + trans[p][cur]; first-max
      float m = (b0 + e) + trc0; int arg = 0;
      float v;
      v = (b1 + e) + trc1; if (v > m) { m = v; arg = 1; }
      v = (b2 + e) + trc2; if (v > m) { m = v; arg = 2; }
      v = (b3 + e) + trc3; if (v > m) { m = v; arg = 3; }
      best = m;
      unsigned av = ((unsigned)arg) << (8 * l);        // pack off-chain
      av |= __shfl_xor(av, 1);
      av |= __shfl_xor(av, 2);
      if (l == 0) btm[ti] = av;
    }
    // final argmax (computed identically on all 4 lanes)
    const float f0 = __shfl(best, 0) + to_EOS[0];
    const float f1 = __shfl(best, 1) + to_EOS[1];
    const float f2 = __shfl(best, 2) + to_EOS[2];
    const float f3 = __shfl(best, 3) + to_EOS[3];
    if (l == 0) {
      float m = f0; int last = 0;
      if (f1 > m) { m = f1; last = 1; }
      if (f2 > m) { m = f2; last = 2; }
      if (f3 > m) { m = f3; last = 3; }
      labs[len - 1] = last;
      int cur = last;
      #pragma unroll 4
      for (int ti = len - 2; ti >= 0; --ti) {
        cur = (int)((btm[ti + 1] >> (8 * cur)) & 255u);
        labs[ti] = cur;
      }
    }
  }
  __syncthreads();
  out[b * TMAX + tid] = (tid < len) ? labs[tid] : 0;
}

// ---------------------------------------------------------------------------
extern "C" void kernel_launch(void* const* d_in, const int* in_sizes, int n_in,
                              void* d_out, int out_size, void* d_ws, size_t ws_size,
                              hipStream_t stream) {
  const int*   pad_seq  = (const int*)d_in[0];
  const int*   lens     = (const int*)d_in[1];
  const float* emb      = (const float*)d_in[2];
  const float* W_ih_f   = (const float*)d_in[3];
  const float* W_hh_f   = (const float*)d_in[4];
  const float* b_ih_f   = (const float*)d_in[5];
  const float* b_hh_f   = (const float*)d_in[6];
  const float* W_ih_b   = (const float*)d_in[7];
  const float* W_hh_b   = (const float*)d_in[8];
  const float* b_ih_b   = (const float*)d_in[9];
  const float* b_hh_b   = (const float*)d_in[10];
  const float* W_lab    = (const float*)d_in[11];
  const float* b_lab    = (const float*)d_in[12];
  const float* trans    = (const float*)d_in[13];
  const float* from_BOS = (const float*)d_in[14];
  const float* to_EOS   = (const float*)d_in[15];
  int* out = (int*)d_out;

  float* embW  = (float*)d_ws;                       // [8000][1024] fp32 = 32.8 MB
  float* h_out = embW + (size_t)VOCAB * NCOL;        // [B][T][256]  fp32 = 67.1 MB

  embw_gemm<<<dim3(63, 8), 256, 0, stream>>>(emb, W_ih_f, W_ih_b,
                                             b_ih_f, b_hh_f, b_ih_b, b_hh_b, embW);
  lstm_rec<<<dim3(2 * BATCH), 512, 0, stream>>>(pad_seq, lens, W_hh_f, W_hh_b,
                                                embW, h_out);
  viterbi_k<<<dim3(BATCH), 512, 0, stream>>>(lens, h_out, W_lab, b_lab, trans,
                                             from_BOS, to_EOS, out);
}

// Round 5
// 748.072 us; speedup vs baseline: 1.2497x; 1.2497x over previous
//
#include <hip/hip_runtime.h>
#include <math.h>

#define VOCAB 8000
#define BATCH 128
#define TMAX  512
#define DIM   256
#define HID   128
#define G4    512     // 4*HID
#define NCOL  1024    // 2*G4 (both directions)

// ---------------------------------------------------------------------------
// Kernel 1: embW[v][n] = emb[v,:] . W_ih_dir[n,:] + b_ih_dir[n] + b_hh_dir[n]
// ---------------------------------------------------------------------------
__global__ __launch_bounds__(256) void embw_gemm(
    const float* __restrict__ emb,
    const float* __restrict__ Wf, const float* __restrict__ Wb,
    const float* __restrict__ bihf, const float* __restrict__ bhhf,
    const float* __restrict__ bihb, const float* __restrict__ bhhb,
    float* __restrict__ embW) {
  __shared__ float As[32][132];   // k-major, padded stride
  __shared__ float Bs[32][132];
  const int tid = threadIdx.x;
  const int m0 = blockIdx.x * 128;
  const int n0 = blockIdx.y * 128;
  const int tx = tid & 15, ty = tid >> 4;
  const int lrow = tid >> 1;            // 0..127
  const int lseg = (tid & 1) * 16;      // 0 or 16 (k offset)
  const float* Wsrc = (n0 < 512) ? Wf : Wb;
  const int nbase = (n0 < 512) ? n0 : (n0 - 512);

  float acc[8][8];
  #pragma unroll
  for (int i = 0; i < 8; ++i)
    #pragma unroll
    for (int jj = 0; jj < 8; ++jj) acc[i][jj] = 0.f;

  for (int k0 = 0; k0 < 256; k0 += 32) {
    const int gm = m0 + lrow;
    #pragma unroll
    for (int q = 0; q < 4; ++q) {
      float4 v = make_float4(0.f, 0.f, 0.f, 0.f);
      if (gm < VOCAB) v = *(const float4*)(emb + (size_t)gm * 256 + k0 + lseg + 4 * q);
      As[lseg + 4*q + 0][lrow] = v.x;
      As[lseg + 4*q + 1][lrow] = v.y;
      As[lseg + 4*q + 2][lrow] = v.z;
      As[lseg + 4*q + 3][lrow] = v.w;
    }
    #pragma unroll
    for (int q = 0; q < 4; ++q) {
      float4 v = *(const float4*)(Wsrc + (size_t)(nbase + lrow) * 256 + k0 + lseg + 4 * q);
      Bs[lseg + 4*q + 0][lrow] = v.x;
      Bs[lseg + 4*q + 1][lrow] = v.y;
      Bs[lseg + 4*q + 2][lrow] = v.z;
      Bs[lseg + 4*q + 3][lrow] = v.w;
    }
    __syncthreads();
    #pragma unroll
    for (int k = 0; k < 32; ++k) {
      float4 av0 = *(const float4*)&As[k][ty * 8];
      float4 av1 = *(const float4*)&As[k][ty * 8 + 4];
      float4 bv0 = *(const float4*)&Bs[k][tx * 4];
      float4 bv1 = *(const float4*)&Bs[k][64 + tx * 4];
      float a[8]  = {av0.x, av0.y, av0.z, av0.w, av1.x, av1.y, av1.z, av1.w};
      float bb[8] = {bv0.x, bv0.y, bv0.z, bv0.w, bv1.x, bv1.y, bv1.z, bv1.w};
      #pragma unroll
      for (int i = 0; i < 8; ++i)
        #pragma unroll
        for (int jj = 0; jj < 8; ++jj)
          acc[i][jj] += a[i] * bb[jj];
    }
    __syncthreads();
  }

  float bias[8];
  #pragma unroll
  for (int jj = 0; jj < 8; ++jj) {
    int n = n0 + ((jj < 4) ? (tx * 4 + jj) : (64 + tx * 4 + (jj - 4)));
    bias[jj] = (n < 512) ? (bihf[n] + bhhf[n]) : (bihb[n - 512] + bhhb[n - 512]);
  }
  #pragma unroll
  for (int i = 0; i < 8; ++i) {
    int gm = m0 + ty * 8 + i;
    if (gm >= VOCAB) continue;
    float4 v0 = make_float4(acc[i][0] + bias[0], acc[i][1] + bias[1],
                            acc[i][2] + bias[2], acc[i][3] + bias[3]);
    float4 v1 = make_float4(acc[i][4] + bias[4], acc[i][5] + bias[5],
                            acc[i][6] + bias[6], acc[i][7] + bias[7]);
    *(float4*)(embW + (size_t)gm * NCOL + n0 + tx * 4) = v0;
    *(float4*)(embW + (size_t)gm * NCOL + n0 + 64 + tx * 4) = v1;
  }
}

// ---------------------------------------------------------------------------
// Kernel 2: masked LSTM recurrence. One block per (seq, dir); 256 blocks =
// 1 per CU. tid = 4*j + g. W_hh row loaded once as float4 (dwordx4), then
// splat into 128 named SCALAR floats each pinned with a 32-bit
// `asm volatile("" : "+v")` — supported tied-operand form (R4: the float4
// "+v" pin hit "tied indirect register inputs" backend error). Volatile asm
// can't be sunk/rematerialized -> weights stay VGPR-resident across the loop
// (R2/R3: plain loads were sunk, 256KB/CU/step L1 re-fetch bound the kernel
// at VALUBusy 34%, 3400 cyc/step).
// ---------------------------------------------------------------------------
#define REP32(M) M(0) M(1) M(2) M(3) M(4) M(5) M(6) M(7) M(8) M(9) M(10) \
  M(11) M(12) M(13) M(14) M(15) M(16) M(17) M(18) M(19) M(20) M(21) M(22) \
  M(23) M(24) M(25) M(26) M(27) M(28) M(29) M(30) M(31)

__global__ __launch_bounds__(512)
__attribute__((amdgpu_waves_per_eu(2, 2)))
void lstm_rec(
    const int* __restrict__ pad_seq, const int* __restrict__ lens,
    const float* __restrict__ Whh_f, const float* __restrict__ Whh_b,
    const float* __restrict__ embW, float* __restrict__ h_out) {
  const int dir = blockIdx.x & 1;
  const int b = blockIdx.x >> 1;
  const int tid = threadIdx.x;
  const int j = tid >> 2;       // hidden unit 0..127
  const int g = tid & 3;        // gate 0..3 (i,f,g,o)
  __shared__ float h_buf[2][HID];
  __shared__ int tok[TMAX];

  tok[tid] = pad_seq[b * TMAX + tid];
  if (tid < HID) h_buf[0][tid] = 0.f;
  const int len = lens[b];
  const float* __restrict__ Whh = dir ? Whh_b : Whh_f;

  // W_hh row (g*HID + j): 32x float4 load -> 128 pinned scalar VGPRs.
  const float4* wr = (const float4*)(Whh + (size_t)(g * HID + j) * HID);
#define DECLW(i)                                                        \
  float w##i##_0, w##i##_1, w##i##_2, w##i##_3;                         \
  { float4 t = wr[i];                                                   \
    w##i##_0 = t.x; w##i##_1 = t.y; w##i##_2 = t.z; w##i##_3 = t.w; }   \
  asm volatile("" : "+v"(w##i##_0));                                    \
  asm volatile("" : "+v"(w##i##_1));                                    \
  asm volatile("" : "+v"(w##i##_2));                                    \
  asm volatile("" : "+v"(w##i##_3));
  REP32(DECLW)
#undef DECLW

  float c = 0.f;
  __syncthreads();

  const float* __restrict__ ecol = embW + dir * G4 + (g * HID + j);
  const int tstep = dir ? -1 : 1;
  int t = dir ? (len - 1) : 0;
  float xw0 = ecol[(size_t)tok[t] * NCOL];                     // step s
  float xw1 = (len > 1) ? ecol[(size_t)tok[t + tstep] * NCOL] : 0.f;  // s+1

  const float ascale = (g == 2) ? 2.f : 1.f;   // tanh via sigmoid for gate 2

  for (int s = 0; s < len; ++s) {
    // depth-2 prefetch: step s+2 (covers ~900cyc HBM-miss latency)
    float xw2 = 0.f;
    if (s + 2 < len) xw2 = ecol[(size_t)tok[t + 2 * tstep] * NCOL];

    const float4* h4 = (const float4*)h_buf[s & 1];
    float a0 = 0.f, a1 = 0.f, a2 = 0.f, a3 = 0.f;
#define MAC(i) { float4 hv = h4[i];                 \
    a0 = fmaf(hv.x, w##i##_0, a0);                  \
    a1 = fmaf(hv.y, w##i##_1, a1);                  \
    a2 = fmaf(hv.z, w##i##_2, a2);                  \
    a3 = fmaf(hv.w, w##i##_3, a3); }
    REP32(MAC)
#undef MAC
    const float a = ((a0 + a1) + (a2 + a3)) + xw0;

    // activate OWN gate: sigmoid for i,f,o; tanh(x)=2*sigmoid(2x)-1 for g
    const float sg = 1.f / (1.f + expf(-ascale * a));
    const float act = (g == 2) ? (2.f * sg - 1.f) : sg;

    // quad exchange of the ACTIVATED gate values
    const float p1 = __shfl_xor(act, 1);    // gate g^1
    const float p2 = __shfl_xor(act, 2);    // gate g^2
    const float p3 = __shfl_xor(p1, 2);     // gate g^3
    const float ev  = (g & 1) ? p1 : act;
    const float od  = (g & 1) ? act : p1;
    const float ev2 = (g & 1) ? p3 : p2;
    const float od2 = (g & 1) ? p2 : p3;
    const float ig = (g & 2) ? ev2 : ev;    // sigmoid(i)
    const float fg = (g & 2) ? od2 : od;    // sigmoid(f)
    const float gt = (g & 2) ? ev  : ev2;   // tanh(g)
    const float og = (g & 2) ? od  : od2;   // sigmoid(o)

    c = fg * c + ig * gt;                   // redundant x4 per quad, identical
    const float sc2 = 1.f / (1.f + expf(-2.f * c));
    const float h = og * (2.f * sc2 - 1.f); // og * tanh(c)

    if (g == 0) {
      h_buf[(s + 1) & 1][j] = h;
      h_out[((size_t)(b * TMAX + t)) * DIM + dir * HID + j] = h;
    }
    __syncthreads();                        // single barrier per step
    xw0 = xw1; xw1 = xw2;
    t += tstep;
  }
}

// ---------------------------------------------------------------------------
// Kernel 3: emissions + Viterbi. DP quad-parallel (lane l = cur label).
// ---------------------------------------------------------------------------
__global__ __launch_bounds__(512) void viterbi_k(
    const int* __restrict__ lens, const float* __restrict__ h_out,
    const float* __restrict__ W_lab, const float* __restrict__ b_lab,
    const float* __restrict__ trans, const float* __restrict__ from_BOS,
    const float* __restrict__ to_EOS, int* __restrict__ out) {
  const int b = blockIdx.x;
  const int tid = threadIdx.x;
  __shared__ float sc[TMAX][4];
  __shared__ unsigned btm[TMAX];
  __shared__ float wl[4][256];
  __shared__ int labs[TMAX];
  const int len = lens[b];

  for (int i = tid; i < 1024; i += 512) wl[i >> 8][i & 255] = W_lab[i];
  __syncthreads();

  if (tid < len) {
    const float4* h4 = (const float4*)(h_out + ((size_t)(b * TMAX + tid)) * DIM);
    float s0 = b_lab[0], s1 = b_lab[1], s2 = b_lab[2], s3 = b_lab[3];
    #pragma unroll 8
    for (int k4 = 0; k4 < 64; ++k4) {
      float4 hv = h4[k4];
      float4 w0 = *(const float4*)&wl[0][4 * k4];
      float4 w1 = *(const float4*)&wl[1][4 * k4];
      float4 w2 = *(const float4*)&wl[2][4 * k4];
      float4 w3 = *(const float4*)&wl[3][4 * k4];
      s0 += hv.x * w0.x + hv.y * w0.y + hv.z * w0.z + hv.w * w0.w;
      s1 += hv.x * w1.x + hv.y * w1.y + hv.z * w1.z + hv.w * w1.w;
      s2 += hv.x * w2.x + hv.y * w2.y + hv.z * w2.z + hv.w * w2.w;
      s3 += hv.x * w3.x + hv.y * w3.y + hv.z * w3.z + hv.w * w3.w;
    }
    *(float4*)&sc[tid][0] = make_float4(s0, s1, s2, s3);
  }
  __syncthreads();

  // --- DP: lanes 0..3 of wave 0, lane l owns cur-label l ---
  if (tid < 4) {
    const int l = tid;
    float trc0 = trans[0 * 4 + l], trc1 = trans[1 * 4 + l];
    float trc2 = trans[2 * 4 + l], trc3 = trans[3 * 4 + l];
    float best = from_BOS[l] + sc[0][l];
    float e_next = sc[1][l];                 // prefetch (unused if len==1)
    for (int ti = 1; ti < len; ++ti) {
      const float e = e_next;
      e_next = sc[(ti + 1 < TMAX) ? ti + 1 : ti][l];   // prefetch next
      const float b0 = __shfl(best, 0);
      const float b1 = __shfl(best, 1);
      const float b2 = __shfl(best, 2);
      const float b3 = __shfl(best, 3);
      // reference add order: (best[p] + e[cur]) + trans[p][cur]; first-max
      float m = (b0 + e) + trc0; int arg = 0;
      float v;
      v = (b1 + e) + trc1; if (v > m) { m = v; arg = 1; }
      v = (b2 + e) + trc2; if (v > m) { m = v; arg = 2; }
      v = (b3 + e) + trc3; if (v > m) { m = v; arg = 3; }
      best = m;
      unsigned av = ((unsigned)arg) << (8 * l);        // pack off-chain
      av |= __shfl_xor(av, 1);
      av |= __shfl_xor(av, 2);
      if (l == 0) btm[ti] = av;
    }
    const float f0 = __shfl(best, 0) + to_EOS[0];
    const float f1 = __shfl(best, 1) + to_EOS[1];
    const float f2 = __shfl(best, 2) + to_EOS[2];
    const float f3 = __shfl(best, 3) + to_EOS[3];
    if (l == 0) {
      float m = f0; int last = 0;
      if (f1 > m) { m = f1; last = 1; }
      if (f2 > m) { m = f2; last = 2; }
      if (f3 > m) { m = f3; last = 3; }
      labs[len - 1] = last;
      int cur = last;
      #pragma unroll 4
      for (int ti = len - 2; ti >= 0; --ti) {
        cur = (int)((btm[ti + 1] >> (8 * cur)) & 255u);
        labs[ti] = cur;
      }
    }
  }
  __syncthreads();
  out[b * TMAX + tid] = (tid < len) ? labs[tid] : 0;
}

// ---------------------------------------------------------------------------
extern "C" void kernel_launch(void* const* d_in, const int* in_sizes, int n_in,
                              void* d_out, int out_size, void* d_ws, size_t ws_size,
                              hipStream_t stream) {
  const int*   pad_seq  = (const int*)d_in[0];
  const int*   lens     = (const int*)d_in[1];
  const float* emb      = (const float*)d_in[2];
  const float* W_ih_f   = (const float*)d_in[3];
  const float* W_hh_f   = (const float*)d_in[4];
  const float* b_ih_f   = (const float*)d_in[5];
  const float* b_hh_f   = (const float*)d_in[6];
  const float* W_ih_b   = (const float*)d_in[7];
  const float* W_hh_b   = (const float*)d_in[8];
  const float* b_ih_b   = (const float*)d_in[9];
  const float* b_hh_b   = (const float*)d_in[10];
  const float* W_lab    = (const float*)d_in[11];
  const float* b_lab    = (const float*)d_in[12];
  const float* trans    = (const float*)d_in[13];
  const float* from_BOS = (const float*)d_in[14];
  const float* to_EOS   = (const float*)d_in[15];
  int* out = (int*)d_out;

  float* embW  = (float*)d_ws;                       // [8000][1024] fp32 = 32.8 MB
  float* h_out = embW + (size_t)VOCAB * NCOL;        // [B][T][256]  fp32 = 67.1 MB

  embw_gemm<<<dim3(63, 8), 256, 0, stream>>>(emb, W_ih_f, W_ih_b,
                                             b_ih_f, b_hh_f, b_ih_b, b_hh_b, embW);
  lstm_rec<<<dim3(2 * BATCH), 512, 0, stream>>>(pad_seq, lens, W_hh_f, W_hh_b,
                                                embW, h_out);
  viterbi_k<<<dim3(BATCH), 512, 0, stream>>>(lens, h_out, W_lab, b_lab, trans,
                                             from_BOS, to_EOS, out);
}

// Round 6
// 683.420 us; speedup vs baseline: 1.3679x; 1.0946x over previous
//
#include <hip/hip_runtime.h>
#include <math.h>

#define VOCAB 8000
#define BATCH 128
#define TMAX  512
#define DIM   256
#define HID   128
#define G4    512     // 4*HID
#define NCOL  1024    // 2*G4 (both directions)

// ---------------------------------------------------------------------------
// Kernel 1: embW[v][n] = emb[v,:] . W_ih_dir[n,:] + b_ih_dir[n] + b_hh_dir[n]
// ---------------------------------------------------------------------------
__global__ __launch_bounds__(256) void embw_gemm(
    const float* __restrict__ emb,
    const float* __restrict__ Wf, const float* __restrict__ Wb,
    const float* __restrict__ bihf, const float* __restrict__ bhhf,
    const float* __restrict__ bihb, const float* __restrict__ bhhb,
    float* __restrict__ embW) {
  __shared__ float As[32][132];   // k-major, padded stride
  __shared__ float Bs[32][132];
  const int tid = threadIdx.x;
  const int m0 = blockIdx.x * 128;
  const int n0 = blockIdx.y * 128;
  const int tx = tid & 15, ty = tid >> 4;
  const int lrow = tid >> 1;            // 0..127
  const int lseg = (tid & 1) * 16;      // 0 or 16 (k offset)
  const float* Wsrc = (n0 < 512) ? Wf : Wb;
  const int nbase = (n0 < 512) ? n0 : (n0 - 512);

  float acc[8][8];
  #pragma unroll
  for (int i = 0; i < 8; ++i)
    #pragma unroll
    for (int jj = 0; jj < 8; ++jj) acc[i][jj] = 0.f;

  for (int k0 = 0; k0 < 256; k0 += 32) {
    const int gm = m0 + lrow;
    #pragma unroll
    for (int q = 0; q < 4; ++q) {
      float4 v = make_float4(0.f, 0.f, 0.f, 0.f);
      if (gm < VOCAB) v = *(const float4*)(emb + (size_t)gm * 256 + k0 + lseg + 4 * q);
      As[lseg + 4*q + 0][lrow] = v.x;
      As[lseg + 4*q + 1][lrow] = v.y;
      As[lseg + 4*q + 2][lrow] = v.z;
      As[lseg + 4*q + 3][lrow] = v.w;
    }
    #pragma unroll
    for (int q = 0; q < 4; ++q) {
      float4 v = *(const float4*)(Wsrc + (size_t)(nbase + lrow) * 256 + k0 + lseg + 4 * q);
      Bs[lseg + 4*q + 0][lrow] = v.x;
      Bs[lseg + 4*q + 1][lrow] = v.y;
      Bs[lseg + 4*q + 2][lrow] = v.z;
      Bs[lseg + 4*q + 3][lrow] = v.w;
    }
    __syncthreads();
    #pragma unroll
    for (int k = 0; k < 32; ++k) {
      float4 av0 = *(const float4*)&As[k][ty * 8];
      float4 av1 = *(const float4*)&As[k][ty * 8 + 4];
      float4 bv0 = *(const float4*)&Bs[k][tx * 4];
      float4 bv1 = *(const float4*)&Bs[k][64 + tx * 4];
      float a[8]  = {av0.x, av0.y, av0.z, av0.w, av1.x, av1.y, av1.z, av1.w};
      float bb[8] = {bv0.x, bv0.y, bv0.z, bv0.w, bv1.x, bv1.y, bv1.z, bv1.w};
      #pragma unroll
      for (int i = 0; i < 8; ++i)
        #pragma unroll
        for (int jj = 0; jj < 8; ++jj)
          acc[i][jj] += a[i] * bb[jj];
    }
    __syncthreads();
  }

  float bias[8];
  #pragma unroll
  for (int jj = 0; jj < 8; ++jj) {
    int n = n0 + ((jj < 4) ? (tx * 4 + jj) : (64 + tx * 4 + (jj - 4)));
    bias[jj] = (n < 512) ? (bihf[n] + bhhf[n]) : (bihb[n - 512] + bhhb[n - 512]);
  }
  #pragma unroll
  for (int i = 0; i < 8; ++i) {
    int gm = m0 + ty * 8 + i;
    if (gm >= VOCAB) continue;
    float4 v0 = make_float4(acc[i][0] + bias[0], acc[i][1] + bias[1],
                            acc[i][2] + bias[2], acc[i][3] + bias[3]);
    float4 v1 = make_float4(acc[i][4] + bias[4], acc[i][5] + bias[5],
                            acc[i][6] + bias[6], acc[i][7] + bias[7]);
    *(float4*)(embW + (size_t)gm * NCOL + n0 + tx * 4) = v0;
    *(float4*)(embW + (size_t)gm * NCOL + n0 + 64 + tx * 4) = v1;
  }
}

// ---------------------------------------------------------------------------
// Kernel 2: masked LSTM recurrence, split-K quad version.
// One block per (seq, dir); 256 blocks = 1 per CU. tid = 4*j + q:
// thread computes ALL 4 gate partials of unit j over h[32q..32q+31]
// (8 ds_read_b128 per step instead of 32 -- R5 showed the h broadcast was
// LDS-pipe-bound: 256 b128/CU/step ~= 2475 cyc, VALUBusy 34%).
// 3-shuffle quad transpose-reduce leaves thread q with gate q's total.
// Weights (4 rows x 32 cols = 128 scalars) pinned via asm volatile (R5:
// effective; allocator parks them in the unified VGPR/AGPR file).
// h stored chunk-padded (stride 36 floats) so the 4 distinct quad addresses
// land in distinct banks.
// ---------------------------------------------------------------------------
#define REP8G(M,G) M(G,0) M(G,1) M(G,2) M(G,3) M(G,4) M(G,5) M(G,6) M(G,7)

__global__ __launch_bounds__(512)
__attribute__((amdgpu_waves_per_eu(2, 2)))
void lstm_rec(
    const int* __restrict__ pad_seq, const int* __restrict__ lens,
    const float* __restrict__ Whh_f, const float* __restrict__ Whh_b,
    const float* __restrict__ embW, float* __restrict__ h_out) {
  const int dir = blockIdx.x & 1;
  const int b = blockIdx.x >> 1;
  const int tid = threadIdx.x;
  const int j = tid >> 2;       // hidden unit 0..127
  const int q = tid & 3;        // K-quarter / final gate owner 0..3
  __shared__ float h_pad[2][4][36];   // [buf][chunk][32 + 4 pad]
  __shared__ int tok[TMAX];

  tok[tid] = pad_seq[b * TMAX + tid];
  if (tid < 144) ((float*)h_pad[0])[tid] = 0.f;
  const int len = lens[b];
  const float* __restrict__ Whh = dir ? Whh_b : Whh_f;

  // Weights: gate rows {0,1,2,3}*HID + j, columns 32q..32q+31.
  const float4* wr0 = (const float4*)(Whh + ((size_t)(0 * HID + j) * HID) + 32 * q);
  const float4* wr1 = (const float4*)(Whh + ((size_t)(1 * HID + j) * HID) + 32 * q);
  const float4* wr2 = (const float4*)(Whh + ((size_t)(2 * HID + j) * HID) + 32 * q);
  const float4* wr3 = (const float4*)(Whh + ((size_t)(3 * HID + j) * HID) + 32 * q);
#define DECLW(G,I)                                                       \
  float w##G##_##I##_0, w##G##_##I##_1, w##G##_##I##_2, w##G##_##I##_3;  \
  { float4 t = wr##G[I];                                                 \
    w##G##_##I##_0 = t.x; w##G##_##I##_1 = t.y;                          \
    w##G##_##I##_2 = t.z; w##G##_##I##_3 = t.w; }                        \
  asm volatile("" : "+v"(w##G##_##I##_0));                               \
  asm volatile("" : "+v"(w##G##_##I##_1));                               \
  asm volatile("" : "+v"(w##G##_##I##_2));                               \
  asm volatile("" : "+v"(w##G##_##I##_3));
  REP8G(DECLW,0)
  REP8G(DECLW,1)
  REP8G(DECLW,2)
  REP8G(DECLW,3)
#undef DECLW

  float c = 0.f;
  __syncthreads();

  // embW column for MY gate (q) of unit j
  const float* __restrict__ ecol = embW + dir * G4 + (q * HID + j);
  const int tstep = dir ? -1 : 1;
  int t = dir ? (len - 1) : 0;
  float xw0 = ecol[(size_t)tok[t] * NCOL];                     // step s
  float xw1 = (len > 1) ? ecol[(size_t)tok[t + tstep] * NCOL] : 0.f;  // s+1

  const float ascale = (q == 2) ? 2.f : 1.f;   // tanh via sigmoid for gate 2
  const int parity = q & 1;
  const int half = (q >> 1) & 1;

  for (int s = 0; s < len; ++s) {
    // depth-2 prefetch: step s+2
    float xw2 = 0.f;
    if (s + 2 < len) xw2 = ecol[(size_t)tok[t + 2 * tstep] * NCOL];

    // my K-quarter of h: 8 float4 (144q-byte base is 16B-aligned)
    const float4* h4 = (const float4*)&h_pad[s & 1][q][0];
    float4 hv0 = h4[0], hv1 = h4[1], hv2 = h4[2], hv3 = h4[3];
    float4 hv4 = h4[4], hv5 = h4[5], hv6 = h4[6], hv7 = h4[7];

    float a00 = 0.f, a01 = 0.f, a02 = 0.f, a03 = 0.f;  // gate 0
    float a10 = 0.f, a11 = 0.f, a12 = 0.f, a13 = 0.f;  // gate 1
    float a20 = 0.f, a21 = 0.f, a22 = 0.f, a23 = 0.f;  // gate 2
    float a30 = 0.f, a31 = 0.f, a32 = 0.f, a33 = 0.f;  // gate 3
#define MACC(G,I)                                        \
    a##G##0 = fmaf(hv##I.x, w##G##_##I##_0, a##G##0);    \
    a##G##1 = fmaf(hv##I.y, w##G##_##I##_1, a##G##1);    \
    a##G##2 = fmaf(hv##I.z, w##G##_##I##_2, a##G##2);    \
    a##G##3 = fmaf(hv##I.w, w##G##_##I##_3, a##G##3);
    REP8G(MACC,0)
    REP8G(MACC,1)
    REP8G(MACC,2)
    REP8G(MACC,3)
#undef MACC
    const float p0 = (a00 + a01) + (a02 + a03);
    const float p1 = (a10 + a11) + (a12 + a13);
    const float p2 = (a20 + a21) + (a22 + a23);
    const float p3 = (a30 + a31) + (a32 + a33);

    // quad transpose-reduce: thread q ends with gate q summed over quarters
    // Stage A (xor 1): keep my-parity gates {parity, parity+2}
    const float keep_lo = parity ? p1 : p0;
    const float keep_hi = parity ? p3 : p2;
    const float send_lo = parity ? p0 : p1;
    const float send_hi = parity ? p2 : p3;
    const float a_lo = keep_lo + __shfl_xor(send_lo, 1);  // gate parity
    const float a_hi = keep_hi + __shfl_xor(send_hi, 1);  // gate parity+2
    // Stage B (xor 2): pick gate q = parity + 2*half
    const float keepB = half ? a_hi : a_lo;
    const float sendB = half ? a_lo : a_hi;
    const float total = keepB + __shfl_xor(sendB, 2);

    const float a = total + xw0;

    // activate OWN gate: sigmoid for i,f,o; tanh(x)=2*sigmoid(2x)-1 for g
    const float sg = 1.f / (1.f + expf(-ascale * a));
    const float act = (q == 2) ? (2.f * sg - 1.f) : sg;

    // quad exchange of the ACTIVATED gate values
    const float e1 = __shfl_xor(act, 1);    // gate q^1
    const float e2 = __shfl_xor(act, 2);    // gate q^2
    const float e3 = __shfl_xor(e1, 2);     // gate q^3
    const float ev  = parity ? e1 : act;
    const float od  = parity ? act : e1;
    const float ev2 = parity ? e3 : e2;
    const float od2 = parity ? e2 : e3;
    const float ig = half ? ev2 : ev;       // sigmoid(i)
    const float fg = half ? od2 : od;       // sigmoid(f)
    const float gt = half ? ev  : ev2;      // tanh(g)
    const float og = half ? od  : od2;      // sigmoid(o)

    c = fg * c + ig * gt;                   // redundant x4 per quad, identical
    const float sc2 = 1.f / (1.f + expf(-2.f * c));
    const float h = og * (2.f * sc2 - 1.f); // og * tanh(c)

    if (q == 0) {
      h_pad[(s + 1) & 1][j >> 5][j & 31] = h;
      h_out[((size_t)(b * TMAX + t)) * DIM + dir * HID + j] = h;
    }
    __syncthreads();                        // single barrier per step
    xw0 = xw1; xw1 = xw2;
    t += tstep;
  }
}

// ---------------------------------------------------------------------------
// Kernel 3: emissions + Viterbi. DP quad-parallel (lane l = cur label).
// ---------------------------------------------------------------------------
__global__ __launch_bounds__(512) void viterbi_k(
    const int* __restrict__ lens, const float* __restrict__ h_out,
    const float* __restrict__ W_lab, const float* __restrict__ b_lab,
    const float* __restrict__ trans, const float* __restrict__ from_BOS,
    const float* __restrict__ to_EOS, int* __restrict__ out) {
  const int b = blockIdx.x;
  const int tid = threadIdx.x;
  __shared__ float sc[TMAX][4];
  __shared__ unsigned btm[TMAX];
  __shared__ float wl[4][256];
  __shared__ int labs[TMAX];
  const int len = lens[b];

  for (int i = tid; i < 1024; i += 512) wl[i >> 8][i & 255] = W_lab[i];
  __syncthreads();

  if (tid < len) {
    const float4* h4 = (const float4*)(h_out + ((size_t)(b * TMAX + tid)) * DIM);
    float s0 = b_lab[0], s1 = b_lab[1], s2 = b_lab[2], s3 = b_lab[3];
    #pragma unroll 8
    for (int k4 = 0; k4 < 64; ++k4) {
      float4 hv = h4[k4];
      float4 w0 = *(const float4*)&wl[0][4 * k4];
      float4 w1 = *(const float4*)&wl[1][4 * k4];
      float4 w2 = *(const float4*)&wl[2][4 * k4];
      float4 w3 = *(const float4*)&wl[3][4 * k4];
      s0 += hv.x * w0.x + hv.y * w0.y + hv.z * w0.z + hv.w * w0.w;
      s1 += hv.x * w1.x + hv.y * w1.y + hv.z * w1.z + hv.w * w1.w;
      s2 += hv.x * w2.x + hv.y * w2.y + hv.z * w2.z + hv.w * w2.w;
      s3 += hv.x * w3.x + hv.y * w3.y + hv.z * w3.z + hv.w * w3.w;
    }
    *(float4*)&sc[tid][0] = make_float4(s0, s1, s2, s3);
  }
  __syncthreads();

  // --- DP: lanes 0..3 of wave 0, lane l owns cur-label l ---
  if (tid < 4) {
    const int l = tid;
    float trc0 = trans[0 * 4 + l], trc1 = trans[1 * 4 + l];
    float trc2 = trans[2 * 4 + l], trc3 = trans[3 * 4 + l];
    float best = from_BOS[l] + sc[0][l];
    float e_next = sc[1][l];                 // prefetch (unused if len==1)
    for (int ti = 1; ti < len; ++ti) {
      const float e = e_next;
      e_next = sc[(ti + 1 < TMAX) ? ti + 1 : ti][l];   // prefetch next
      const float b0 = __shfl(best, 0);
      const float b1 = __shfl(best, 1);
      const float b2 = __shfl(best, 2);
      const float b3 = __shfl(best, 3);
      // reference add order: (best[p] + e[cur]) + trans[p][cur]; first-max
      float m = (b0 + e) + trc0; int arg = 0;
      float v;
      v = (b1 + e) + trc1; if (v > m) { m = v; arg = 1; }
      v = (b2 + e) + trc2; if (v > m) { m = v; arg = 2; }
      v = (b3 + e) + trc3; if (v > m) { m = v; arg = 3; }
      best = m;
      unsigned av = ((unsigned)arg) << (8 * l);        // pack off-chain
      av |= __shfl_xor(av, 1);
      av |= __shfl_xor(av, 2);
      if (l == 0) btm[ti] = av;
    }
    const float f0 = __shfl(best, 0) + to_EOS[0];
    const float f1 = __shfl(best, 1) + to_EOS[1];
    const float f2 = __shfl(best, 2) + to_EOS[2];
    const float f3 = __shfl(best, 3) + to_EOS[3];
    if (l == 0) {
      float m = f0; int last = 0;
      if (f1 > m) { m = f1; last = 1; }
      if (f2 > m) { m = f2; last = 2; }
      if (f3 > m) { m = f3; last = 3; }
      labs[len - 1] = last;
      int cur = last;
      #pragma unroll 4
      for (int ti = len - 2; ti >= 0; --ti) {
        cur = (int)((btm[ti + 1] >> (8 * cur)) & 255u);
        labs[ti] = cur;
      }
    }
  }
  __syncthreads();
  out[b * TMAX + tid] = (tid < len) ? labs[tid] : 0;
}

// ---------------------------------------------------------------------------
extern "C" void kernel_launch(void* const* d_in, const int* in_sizes, int n_in,
                              void* d_out, int out_size, void* d_ws, size_t ws_size,
                              hipStream_t stream) {
  const int*   pad_seq  = (const int*)d_in[0];
  const int*   lens     = (const int*)d_in[1];
  const float* emb      = (const float*)d_in[2];
  const float* W_ih_f   = (const float*)d_in[3];
  const float* W_hh_f   = (const float*)d_in[4];
  const float* b_ih_f   = (const float*)d_in[5];
  const float* b_hh_f   = (const float*)d_in[6];
  const float* W_ih_b   = (const float*)d_in[7];
  const float* W_hh_b   = (const float*)d_in[8];
  const float* b_ih_b   = (const float*)d_in[9];
  const float* b_hh_b   = (const float*)d_in[10];
  const float* W_lab    = (const float*)d_in[11];
  const float* b_lab    = (const float*)d_in[12];
  const float* trans    = (const float*)d_in[13];
  const float* from_BOS = (const float*)d_in[14];
  const float* to_EOS   = (const float*)d_in[15];
  int* out = (int*)d_out;

  float* embW  = (float*)d_ws;                       // [8000][1024] fp32 = 32.8 MB
  float* h_out = embW + (size_t)VOCAB * NCOL;        // [B][T][256]  fp32 = 67.1 MB

  embw_gemm<<<dim3(63, 8), 256, 0, stream>>>(emb, W_ih_f, W_ih_b,
                                             b_ih_f, b_hh_f, b_ih_b, b_hh_b, embW);
  lstm_rec<<<dim3(2 * BATCH), 512, 0, stream>>>(pad_seq, lens, W_hh_f, W_hh_b,
                                                embW, h_out);
  viterbi_k<<<dim3(BATCH), 512, 0, stream>>>(lens, h_out, W_lab, b_lab, trans,
                                             from_BOS, to_EOS, out);
}